// Round 1
// baseline (869.959 us; speedup 1.0000x reference)
//
#include <hip/hip_runtime.h>
#include <hip/hip_bf16.h>
#include <math.h>

// ---------------------------------------------------------------------------
// SimpleMoEModel: dense GEMM -> top1-MoE -> top1-MoE -> residual -> mean ->
// log_softmax -> NLL.  B=8 S=2048 D=1024 E=8, capacity = T/E = 2048.
//
// Design (round 0 baseline, correctness-first but MFMA-based):
//  - All big GEMMs in bf16 MFMA (16x16x32), fp32 accumulate. 128x128 tile,
//    BK=32, 4 waves/block each computing a 64x64 subtile (4x4 accs).
//  - MoE dispatch is a GATHER: scan kernel builds tok_for_slot[e][c] in token
//    order (matches jnp.cumsum capacity-drop semantics exactly); expert GEMM
//    reads gathered rows, epilogue scatters gate*(acc+bias) to out[t].
//  - Dropped tokens produce 0 rows via memset of the output buffer; their
//    exact-zero rows then route deterministically to expert 0 in the next
//    layer (argmax strict-> picks first index on exact ties, like jnp).
//  - Activations stored bf16 in ws (h, o1, o2: 3 x 32 MB).
// ---------------------------------------------------------------------------

#define TOKS 16384
#define DIM 1024
#define NEXP 8
#define CAP 2048
#define BATCH 8
#define SEQ 2048

typedef __bf16 bf16_t;
typedef __bf16 bf16x8 __attribute__((ext_vector_type(8)));
typedef float fx4 __attribute__((ext_vector_type(4)));

// ---------------- dense GEMM: h[T,D] = x[T,D] @ W[D,D] + b, out bf16 --------
__global__ __launch_bounds__(256) void k_gemm_dense(
    const float* __restrict__ A, const float* __restrict__ W,
    const float* __restrict__ bias, bf16_t* __restrict__ out) {
  __shared__ alignas(16) bf16_t As[128][40];  // [m][k], +8 pad breaks conflicts
  __shared__ alignas(16) bf16_t Bs[128][40];  // [n][k] (transposed)
  const int tid = threadIdx.x;
  const int lane = tid & 63, wave = tid >> 6;
  const int quad = lane >> 4, l15 = lane & 15;
  const int wr = (wave >> 1) * 64, wc = (wave & 1) * 64;
  const int n0 = blockIdx.x * 128;
  const int m0 = blockIdx.y * 128;

  fx4 acc[4][4];
#pragma unroll
  for (int i = 0; i < 4; i++)
#pragma unroll
    for (int j = 0; j < 4; j++) acc[i][j] = (fx4)0.0f;

  for (int k0 = 0; k0 < DIM; k0 += 32) {
    // stage A tile 128x32 (fp32 -> bf16)
#pragma unroll
    for (int i = 0; i < 4; i++) {
      int q = tid + 256 * i;
      int r = q >> 3, c = q & 7;
      float4 v = *(const float4*)&A[(size_t)(m0 + r) * DIM + k0 + c * 4];
      bf16_t* d = &As[r][c * 4];
      d[0] = (bf16_t)v.x; d[1] = (bf16_t)v.y; d[2] = (bf16_t)v.z; d[3] = (bf16_t)v.w;
    }
    // stage B tile 32x128 transposed into Bs[n][k]
#pragma unroll
    for (int i = 0; i < 4; i++) {
      int q = tid + 256 * i;
      int r = q >> 5, c = q & 31;
      float4 v = *(const float4*)&W[(size_t)(k0 + r) * DIM + n0 + c * 4];
      Bs[c * 4 + 0][r] = (bf16_t)v.x;
      Bs[c * 4 + 1][r] = (bf16_t)v.y;
      Bs[c * 4 + 2][r] = (bf16_t)v.z;
      Bs[c * 4 + 3][r] = (bf16_t)v.w;
    }
    __syncthreads();
    bf16x8 av[4], bv[4];
#pragma unroll
    for (int i = 0; i < 4; i++) av[i] = *(const bf16x8*)&As[wr + i * 16 + l15][quad * 8];
#pragma unroll
    for (int j = 0; j < 4; j++) bv[j] = *(const bf16x8*)&Bs[wc + j * 16 + l15][quad * 8];
#pragma unroll
    for (int i = 0; i < 4; i++)
#pragma unroll
      for (int j = 0; j < 4; j++)
        acc[i][j] = __builtin_amdgcn_mfma_f32_16x16x32_bf16(av[i], bv[j], acc[i][j], 0, 0, 0);
    __syncthreads();
  }
#pragma unroll
  for (int j = 0; j < 4; j++) {
    int col = n0 + wc + j * 16 + l15;
    float bb = bias[col];
#pragma unroll
    for (int i = 0; i < 4; i++)
#pragma unroll
      for (int r = 0; r < 4; r++) {
        int m = m0 + wr + i * 16 + quad * 4 + r;  // verified C/D layout (m89/m91)
        out[(size_t)m * DIM + col] = (bf16_t)(acc[i][j][r] + bb);
      }
  }
}

// ---------------- gating: logits=act@Wg, softmax, top1 ---------------------
__global__ __launch_bounds__(256) void k_gate(
    const bf16_t* __restrict__ act, const float* __restrict__ Wg,
    int* __restrict__ idx, float* __restrict__ gate) {
  const int t = blockIdx.x * 4 + (threadIdx.x >> 6);
  const int lane = threadIdx.x & 63;
  float acc[8] = {0.f, 0.f, 0.f, 0.f, 0.f, 0.f, 0.f, 0.f};
  const bf16_t* a = act + (size_t)t * DIM;
  for (int d = lane; d < DIM; d += 64) {
    float av = (float)a[d];
    float4 w0 = *(const float4*)&Wg[d * 8];
    float4 w1 = *(const float4*)&Wg[d * 8 + 4];
    acc[0] += av * w0.x; acc[1] += av * w0.y; acc[2] += av * w0.z; acc[3] += av * w0.w;
    acc[4] += av * w1.x; acc[5] += av * w1.y; acc[6] += av * w1.z; acc[7] += av * w1.w;
  }
#pragma unroll
  for (int off = 32; off; off >>= 1)
#pragma unroll
    for (int e = 0; e < 8; e++) acc[e] += __shfl_xor(acc[e], off);
  if (lane == 0) {
    float best = acc[0];
    int bi = 0;
#pragma unroll
    for (int e = 1; e < 8; e++)
      if (acc[e] > best) { best = acc[e]; bi = e; }  // strict >: first max wins
    float s = 0.f;
#pragma unroll
    for (int e = 0; e < 8; e++) s += expf(acc[e] - best);
    idx[t] = bi;
    gate[t] = 1.0f / s;  // softmax prob of the argmax expert
  }
}

// ---------------- routing scan (token-order capacity drop) -----------------
__global__ __launch_bounds__(256) void k_scan(
    const int* __restrict__ idx, int* __restrict__ tok, int* __restrict__ cnt) {
  __shared__ int ex[256][8];
  const int tid = threadIdx.x;
  int c[8] = {0, 0, 0, 0, 0, 0, 0, 0};
  const int b0 = tid * 64;
  for (int i = 0; i < 64; i++) c[idx[b0 + i]]++;
#pragma unroll
  for (int e = 0; e < 8; e++) ex[tid][e] = c[e];
  __syncthreads();
  if (tid < 8) {
    int run = 0;
    for (int j = 0; j < 256; j++) { int v = ex[j][tid]; ex[j][tid] = run; run += v; }
    cnt[tid] = run < CAP ? run : CAP;
  }
  __syncthreads();
  int run[8];
#pragma unroll
  for (int e = 0; e < 8; e++) run[e] = ex[tid][e];
  for (int i = 0; i < 64; i++) {
    int t = b0 + i;
    int e = idx[t];
    int pos = run[e]++;
    if (pos < CAP) tok[e * CAP + pos] = t;
  }
}

// ---------------- expert GEMM with gathered A rows + combine epilogue ------
__global__ __launch_bounds__(256) void k_gemm_expert(
    const bf16_t* __restrict__ Ain, const float* __restrict__ We,
    const float* __restrict__ be, const int* __restrict__ tok,
    const int* __restrict__ cnt, const float* __restrict__ gate,
    bf16_t* __restrict__ outp) {
  const int e = blockIdx.z;
  const int count = cnt[e];
  const int c0 = blockIdx.y * 128;
  if (c0 >= count) return;
  const int n0 = blockIdx.x * 128;
  const float* W = We + (size_t)e * DIM * DIM;
  const float* bias = be + (size_t)e * DIM;
  const int* tk = tok + e * CAP;

  __shared__ alignas(16) bf16_t As[128][40];
  __shared__ alignas(16) bf16_t Bs[128][40];
  const int tid = threadIdx.x;
  const int lane = tid & 63, wave = tid >> 6;
  const int quad = lane >> 4, l15 = lane & 15;
  const int wr = (wave >> 1) * 64, wc = (wave & 1) * 64;

  const int ra = tid >> 2, ca = (tid & 3) * 8;  // each thread: 2 fixed rows, 16B chunk
  const int t0 = (c0 + ra) < count ? tk[c0 + ra] : -1;
  const int t1 = (c0 + 64 + ra) < count ? tk[c0 + 64 + ra] : -1;
  const bf16_t* src0 = (t0 >= 0) ? Ain + (size_t)t0 * DIM : nullptr;
  const bf16_t* src1 = (t1 >= 0) ? Ain + (size_t)t1 * DIM : nullptr;

  fx4 acc[4][4];
#pragma unroll
  for (int i = 0; i < 4; i++)
#pragma unroll
    for (int j = 0; j < 4; j++) acc[i][j] = (fx4)0.0f;

  const uint4 zed = {0u, 0u, 0u, 0u};
  for (int k0 = 0; k0 < DIM; k0 += 32) {
    *(uint4*)&As[ra][ca] = src0 ? *(const uint4*)(src0 + k0 + ca) : zed;
    *(uint4*)&As[ra + 64][ca] = src1 ? *(const uint4*)(src1 + k0 + ca) : zed;
#pragma unroll
    for (int i = 0; i < 4; i++) {
      int q = tid + 256 * i;
      int r = q >> 5, c = q & 31;
      float4 v = *(const float4*)&W[(size_t)(k0 + r) * DIM + n0 + c * 4];
      Bs[c * 4 + 0][r] = (bf16_t)v.x;
      Bs[c * 4 + 1][r] = (bf16_t)v.y;
      Bs[c * 4 + 2][r] = (bf16_t)v.z;
      Bs[c * 4 + 3][r] = (bf16_t)v.w;
    }
    __syncthreads();
    bf16x8 av[4], bv[4];
#pragma unroll
    for (int i = 0; i < 4; i++) av[i] = *(const bf16x8*)&As[wr + i * 16 + l15][quad * 8];
#pragma unroll
    for (int j = 0; j < 4; j++) bv[j] = *(const bf16x8*)&Bs[wc + j * 16 + l15][quad * 8];
#pragma unroll
    for (int i = 0; i < 4; i++)
#pragma unroll
      for (int j = 0; j < 4; j++)
        acc[i][j] = __builtin_amdgcn_mfma_f32_16x16x32_bf16(av[i], bv[j], acc[i][j], 0, 0, 0);
    __syncthreads();
  }
  // combine: out[t] = gate[t] * (acc + be[e]); dropped tokens stay memset-0
#pragma unroll
  for (int i = 0; i < 4; i++)
#pragma unroll
    for (int r = 0; r < 4; r++) {
      int c = c0 + wr + i * 16 + quad * 4 + r;
      if (c < count) {
        int t = tk[c];
        float g = gate[t];
#pragma unroll
        for (int j = 0; j < 4; j++) {
          int col = n0 + wc + j * 16 + l15;
          outp[(size_t)t * DIM + col] = (bf16_t)((acc[i][j][r] + bias[col]) * g);
        }
      }
    }
}

// ---------------- residual mean over S: sent[b,d] = mean_s(h + o2) ---------
__global__ __launch_bounds__(256) void k_reduce_sent(
    const bf16_t* __restrict__ h, const bf16_t* __restrict__ o2,
    float* __restrict__ sent) {
  const int d = blockIdx.x * 256 + threadIdx.x;
  const int b = blockIdx.y;
  const size_t base = (size_t)b * SEQ * DIM + d;
  float s = 0.f;
  for (int ss = 0; ss < SEQ; ss++)
    s += (float)h[base + (size_t)ss * DIM] + (float)o2[base + (size_t)ss * DIM];
  sent[b * DIM + d] = s * (1.0f / SEQ);
}

// ---------------- loss: -mean_b log_softmax(sent)[b, y[b]] -----------------
__global__ __launch_bounds__(256) void k_loss(
    const float* __restrict__ sent, const int* __restrict__ y,
    float* __restrict__ out) {
  __shared__ float red[256];
  const int tid = threadIdx.x;
  float total = 0.f;
  for (int b = 0; b < BATCH; b++) {
    const float* sb = sent + b * DIM;
    float m = -1e30f;
    for (int d = tid; d < DIM; d += 256) m = fmaxf(m, sb[d]);
    red[tid] = m;
    __syncthreads();
    for (int s = 128; s; s >>= 1) {
      if (tid < s) red[tid] = fmaxf(red[tid], red[tid + s]);
      __syncthreads();
    }
    m = red[0];
    __syncthreads();
    float sum = 0.f;
    for (int d = tid; d < DIM; d += 256) sum += expf(sb[d] - m);
    red[tid] = sum;
    __syncthreads();
    for (int s = 128; s; s >>= 1) {
      if (tid < s) red[tid] += red[tid + s];
      __syncthreads();
    }
    if (tid == 0) total += m + logf(red[0]) - sb[y[b]];
    __syncthreads();
  }
  if (tid == 0) out[0] = total * (1.0f / BATCH);
}

// ---------------------------------------------------------------------------
extern "C" void kernel_launch(void* const* d_in, const int* in_sizes, int n_in,
                              void* d_out, int out_size, void* d_ws, size_t ws_size,
                              hipStream_t stream) {
  (void)in_sizes; (void)n_in; (void)out_size; (void)ws_size;
  const float* x   = (const float*)d_in[0];
  const int*   y   = (const int*)d_in[1];
  const float* W1  = (const float*)d_in[2];
  const float* b1  = (const float*)d_in[3];
  const float* Wg2 = (const float*)d_in[4];
  const float* We2 = (const float*)d_in[5];
  const float* be2 = (const float*)d_in[6];
  const float* Wg3 = (const float*)d_in[7];
  const float* We3 = (const float*)d_in[8];
  const float* be3 = (const float*)d_in[9];

  char* p = (char*)d_ws;
  size_t off = 0;
  auto carve = [&](size_t bytes) -> char* {
    char* r = p + off;
    off += (bytes + 255) & ~(size_t)255;
    return r;
  };
  bf16_t* h    = (bf16_t*)carve((size_t)TOKS * DIM * 2);
  bf16_t* o1   = (bf16_t*)carve((size_t)TOKS * DIM * 2);
  bf16_t* o2   = (bf16_t*)carve((size_t)TOKS * DIM * 2);
  int*    idx  = (int*)carve(TOKS * 4);
  float*  gate = (float*)carve(TOKS * 4);
  int*    tok  = (int*)carve(NEXP * CAP * 4);
  int*    cnt  = (int*)carve(NEXP * 4);
  float*  sent = (float*)carve(BATCH * DIM * 4);

  // dropped tokens must read back as exact zeros in both MoE outputs
  hipMemsetAsync(o1, 0, (size_t)TOKS * DIM * 2, stream);
  hipMemsetAsync(o2, 0, (size_t)TOKS * DIM * 2, stream);

  // dense pre-layer
  k_gemm_dense<<<dim3(DIM / 128, TOKS / 128), 256, 0, stream>>>(x, W1, b1, h);

  // MoE layer 2
  k_gate<<<TOKS / 4, 256, 0, stream>>>(h, Wg2, idx, gate);
  k_scan<<<1, 256, 0, stream>>>(idx, tok, cnt);
  k_gemm_expert<<<dim3(DIM / 128, CAP / 128, NEXP), 256, 0, stream>>>(
      h, We2, be2, tok, cnt, gate, o1);

  // MoE layer 3
  k_gate<<<TOKS / 4, 256, 0, stream>>>(o1, Wg3, idx, gate);
  k_scan<<<1, 256, 0, stream>>>(idx, tok, cnt);
  k_gemm_expert<<<dim3(DIM / 128, CAP / 128, NEXP), 256, 0, stream>>>(
      o1, We3, be3, tok, cnt, gate, o2);

  // residual + sentence mean + CE loss
  k_reduce_sent<<<dim3(DIM / 256, BATCH), 256, 0, stream>>>(h, o2, sent);
  k_loss<<<1, 256, 0, stream>>>(sent, y, (float*)d_out);
}

// Round 2
// 581.981 us; speedup vs baseline: 1.4948x; 1.4948x over previous
//
#include <hip/hip_runtime.h>
#include <hip/hip_bf16.h>
#include <math.h>

// ---------------------------------------------------------------------------
// SimpleMoEModel: dense GEMM -> top1-MoE -> top1-MoE -> residual -> mean ->
// log_softmax -> NLL.  B=8 S=2048 D=1024 E=8, capacity = T/E = 2048.
//
// Round 2: m97-style GEMMs.
//  - One-time prep: weights fp32 -> bf16 TRANSPOSED [N][K] in ws; x -> bf16.
//  - GEMM staging via __builtin_amdgcn_global_load_lds width=16 (no VGPR
//    round-trip, conflict-free LDS writes), unpadded [128][32] tiles.
//  - XOR chunk swizzle folded into the GLOBAL address so the linear
//    lane->LDS mapping of global_load_lds lands the swizzled layout;
//    fragment ds_read_b128 conflicts drop to 2-way (free, m136).
//  - Parallel scan (Hillis-Steele), vectorized gating, parallel reduce.
// ---------------------------------------------------------------------------

#define TOKS 16384
#define DIM 1024
#define NEXP 8
#define CAP 2048
#define BATCH 8
#define SEQ 2048

typedef __bf16 bf16_t;
typedef __bf16 bf16x8 __attribute__((ext_vector_type(8)));
typedef float fx4 __attribute__((ext_vector_type(4)));

__device__ __forceinline__ void gll16(const bf16_t* g, bf16_t* l) {
  __builtin_amdgcn_global_load_lds(
      (const __attribute__((address_space(1))) unsigned int*)g,
      (__attribute__((address_space(3))) unsigned int*)l, 16, 0, 0);
}

// ---------------- weight prep: Wt[m][n][k] = (bf16)Wsrc[m][k][n] -----------
// m: 0 = W1, 1..8 = We2[e], 9..16 = We3[e].
__global__ __launch_bounds__(256) void k_prep_w(
    const float* __restrict__ W1, const float* __restrict__ We2,
    const float* __restrict__ We3, bf16_t* __restrict__ Wt) {
  __shared__ float t[64][65];
  const int m = blockIdx.z;
  const float* src = (m == 0) ? W1
                     : (m <= 8) ? We2 + (size_t)(m - 1) * DIM * DIM
                                : We3 + (size_t)(m - 9) * DIM * DIM;
  bf16_t* dst = Wt + (size_t)m * DIM * DIM;
  const int n0 = blockIdx.x * 64, k0 = blockIdx.y * 64;
  const int tid = threadIdx.x;
  const int r = tid >> 4, c4 = (tid & 15) * 4;
#pragma unroll
  for (int i = 0; i < 4; i++) {
    float4 v = *(const float4*)&src[(size_t)(k0 + i * 16 + r) * DIM + n0 + c4];
    t[i * 16 + r][c4] = v.x;
    t[i * 16 + r][c4 + 1] = v.y;
    t[i * 16 + r][c4 + 2] = v.z;
    t[i * 16 + r][c4 + 3] = v.w;
  }
  __syncthreads();
#pragma unroll
  for (int i = 0; i < 4; i++) {
    int rn = i * 16 + r;
    union { bf16_t b[4]; uint2 u; } tmp;
#pragma unroll
    for (int j = 0; j < 4; j++) tmp.b[j] = (bf16_t)t[c4 + j][rn];
    *(uint2*)&dst[(size_t)(n0 + rn) * DIM + k0 + c4] = tmp.u;
  }
}

// ---------------- x fp32 -> bf16 -------------------------------------------
__global__ __launch_bounds__(256) void k_cvt_x(const float* __restrict__ x,
                                               bf16_t* __restrict__ xb) {
  size_t i = ((size_t)blockIdx.x * 256 + threadIdx.x) * 8;
  float4 a = *(const float4*)&x[i];
  float4 b = *(const float4*)&x[i + 4];
  union { bf16_t h[8]; uint4 u; } t;
  t.h[0] = (bf16_t)a.x; t.h[1] = (bf16_t)a.y; t.h[2] = (bf16_t)a.z; t.h[3] = (bf16_t)a.w;
  t.h[4] = (bf16_t)b.x; t.h[5] = (bf16_t)b.y; t.h[6] = (bf16_t)b.z; t.h[7] = (bf16_t)b.w;
  *(uint4*)&xb[i] = t.u;
}

// ---------------- dense GEMM: h = xb @ W1 + b1 (m97 structure) -------------
__global__ __launch_bounds__(256) void k_gemm_dense(
    const bf16_t* __restrict__ A, const bf16_t* __restrict__ Bt,
    const float* __restrict__ bias, bf16_t* __restrict__ out) {
  __shared__ alignas(16) bf16_t As[128 * 32];
  __shared__ alignas(16) bf16_t Bs[128 * 32];
  const int tid = threadIdx.x;
  const int lane = tid & 63, wave = tid >> 6;
  const int quad = lane >> 4, l15 = lane & 15;
  const int wr = (wave >> 1) * 64, wc = (wave & 1) * 64;
  const int n0 = blockIdx.x * 128, m0 = blockIdx.y * 128;
  const int lrow = lane >> 2;
  const int lchunk = (lane & 3) ^ ((lane >> 3) & 3);   // swizzled global chunk
  const int sw8 = (quad ^ ((l15 >> 1) & 3)) << 3;      // swizzled LDS read col

  const bf16_t* gA0 = A + (size_t)(m0 + wave * 32 + lrow) * DIM + lchunk * 8;
  const bf16_t* gA1 = gA0 + (size_t)16 * DIM;
  const bf16_t* gB0 = Bt + (size_t)(n0 + wave * 32 + lrow) * DIM + lchunk * 8;
  const bf16_t* gB1 = gB0 + (size_t)16 * DIM;
  bf16_t* lA0 = &As[(wave * 32) * 32];
  bf16_t* lA1 = &As[(wave * 32 + 16) * 32];
  bf16_t* lB0 = &Bs[(wave * 32) * 32];
  bf16_t* lB1 = &Bs[(wave * 32 + 16) * 32];

  fx4 acc[4][4];
#pragma unroll
  for (int i = 0; i < 4; i++)
#pragma unroll
    for (int j = 0; j < 4; j++) acc[i][j] = (fx4)0.0f;

  for (int k0 = 0; k0 < DIM; k0 += 32) {
    gll16(gA0 + k0, lA0);
    gll16(gA1 + k0, lA1);
    gll16(gB0 + k0, lB0);
    gll16(gB1 + k0, lB1);
    __syncthreads();
    bf16x8 av[4], bv[4];
#pragma unroll
    for (int i = 0; i < 4; i++) av[i] = *(const bf16x8*)&As[(wr + i * 16 + l15) * 32 + sw8];
#pragma unroll
    for (int j = 0; j < 4; j++) bv[j] = *(const bf16x8*)&Bs[(wc + j * 16 + l15) * 32 + sw8];
#pragma unroll
    for (int i = 0; i < 4; i++)
#pragma unroll
      for (int j = 0; j < 4; j++)
        acc[i][j] = __builtin_amdgcn_mfma_f32_16x16x32_bf16(av[i], bv[j], acc[i][j], 0, 0, 0);
    __syncthreads();
  }
#pragma unroll
  for (int j = 0; j < 4; j++) {
    int col = n0 + wc + j * 16 + l15;
    float bb = bias[col];
#pragma unroll
    for (int i = 0; i < 4; i++)
#pragma unroll
      for (int r = 0; r < 4; r++) {
        int m = m0 + wr + i * 16 + quad * 4 + r;  // verified C/D layout (m89/m91)
        out[(size_t)m * DIM + col] = (bf16_t)(acc[i][j][r] + bb);
      }
  }
}

// ---------------- gating: logits=act@Wg, softmax prob of argmax ------------
__global__ __launch_bounds__(256) void k_gate(
    const bf16_t* __restrict__ act, const float* __restrict__ Wg,
    int* __restrict__ idx, float* __restrict__ gate) {
  const int t = blockIdx.x * 4 + (threadIdx.x >> 6);
  const int lane = threadIdx.x & 63;
  const bf16_t* a = act + (size_t)t * DIM + lane * 16;
  union { bf16_t b[8]; uint4 u; } x0, x1;
  x0.u = *(const uint4*)a;
  x1.u = *(const uint4*)(a + 8);
  float av[16];
#pragma unroll
  for (int j = 0; j < 8; j++) { av[j] = (float)x0.b[j]; av[8 + j] = (float)x1.b[j]; }
  float acc[8] = {0.f, 0.f, 0.f, 0.f, 0.f, 0.f, 0.f, 0.f};
  const float* wg = Wg + (size_t)lane * 16 * 8;
#pragma unroll
  for (int d = 0; d < 16; d++) {
    float4 w0 = *(const float4*)&wg[d * 8];
    float4 w1 = *(const float4*)&wg[d * 8 + 4];
    acc[0] += av[d] * w0.x; acc[1] += av[d] * w0.y;
    acc[2] += av[d] * w0.z; acc[3] += av[d] * w0.w;
    acc[4] += av[d] * w1.x; acc[5] += av[d] * w1.y;
    acc[6] += av[d] * w1.z; acc[7] += av[d] * w1.w;
  }
#pragma unroll
  for (int off = 32; off; off >>= 1)
#pragma unroll
    for (int e = 0; e < 8; e++) acc[e] += __shfl_xor(acc[e], off);
  if (lane == 0) {
    float best = acc[0];
    int bi = 0;
#pragma unroll
    for (int e = 1; e < 8; e++)
      if (acc[e] > best) { best = acc[e]; bi = e; }  // strict >: first max wins
    float s = 0.f;
#pragma unroll
    for (int e = 0; e < 8; e++) s += expf(acc[e] - best);
    idx[t] = bi;
    gate[t] = 1.0f / s;
  }
}

// ---------------- routing scan (token-order capacity drop) -----------------
__global__ __launch_bounds__(256) void k_scan(
    const int* __restrict__ idx, int* __restrict__ tok, int* __restrict__ cnt) {
  __shared__ int ex[256][8];
  const int tid = threadIdx.x;
  int c[8] = {0, 0, 0, 0, 0, 0, 0, 0};
  const int4* p = (const int4*)(idx + tid * 64);
#pragma unroll 4
  for (int i = 0; i < 16; i++) {
    int4 v = p[i];
    c[v.x]++; c[v.y]++; c[v.z]++; c[v.w]++;
  }
#pragma unroll
  for (int e = 0; e < 8; e++) ex[tid][e] = c[e];
  __syncthreads();
  for (int off = 1; off < 256; off <<= 1) {
    int add[8];
    if (tid >= off)
#pragma unroll
      for (int e = 0; e < 8; e++) add[e] = ex[tid - off][e];
    __syncthreads();
    if (tid >= off)
#pragma unroll
      for (int e = 0; e < 8; e++) ex[tid][e] += add[e];
    __syncthreads();
  }
  int run[8];
#pragma unroll
  for (int e = 0; e < 8; e++) run[e] = ex[tid][e] - c[e];  // exclusive prefix
  if (tid == 255)
#pragma unroll
    for (int e = 0; e < 8; e++) cnt[e] = ex[255][e] < CAP ? ex[255][e] : CAP;
  const int b0 = tid * 64;
#pragma unroll 4
  for (int i = 0; i < 16; i++) {
    int4 v = p[i];
    int ts[4] = {v.x, v.y, v.z, v.w};
#pragma unroll
    for (int j = 0; j < 4; j++) {
      int e = ts[j];
      int pos = run[e]++;
      if (pos < CAP) tok[e * CAP + pos] = b0 + i * 4 + j;
    }
  }
}

// ---------------- expert GEMM with gathered A + combine epilogue -----------
__global__ __launch_bounds__(256) void k_gemm_expert(
    const bf16_t* __restrict__ Ain, const bf16_t* __restrict__ Wt,
    const float* __restrict__ be, const int* __restrict__ tok,
    const int* __restrict__ cnt, const float* __restrict__ gate,
    const bf16_t* __restrict__ zp, bf16_t* __restrict__ outp) {
  const int e = blockIdx.z;
  const int count = cnt[e];
  const int c0 = blockIdx.y * 128;
  if (c0 >= count) return;
  const int n0 = blockIdx.x * 128;
  const bf16_t* Bt = Wt + (size_t)e * DIM * DIM;
  const float* bias = be + (size_t)e * DIM;
  const int* tk = tok + e * CAP;

  __shared__ alignas(16) bf16_t As[128 * 32];
  __shared__ alignas(16) bf16_t Bs[128 * 32];
  const int tid = threadIdx.x;
  const int lane = tid & 63, wave = tid >> 6;
  const int quad = lane >> 4, l15 = lane & 15;
  const int wr = (wave >> 1) * 64, wc = (wave & 1) * 64;
  const int lrow = lane >> 2;
  const int lchunk = (lane & 3) ^ ((lane >> 3) & 3);
  const int sw8 = (quad ^ ((l15 >> 1) & 3)) << 3;

  const int ca0 = c0 + wave * 32 + lrow;
  const int ca1 = ca0 + 16;
  const bf16_t* gA0 = (ca0 < count)
      ? Ain + (size_t)tk[ca0] * DIM + lchunk * 8 : zp;
  const bf16_t* gA1 = (ca1 < count)
      ? Ain + (size_t)tk[ca1] * DIM + lchunk * 8 : zp;
  const bf16_t* gB0 = Bt + (size_t)(n0 + wave * 32 + lrow) * DIM + lchunk * 8;
  const bf16_t* gB1 = gB0 + (size_t)16 * DIM;
  bf16_t* lA0 = &As[(wave * 32) * 32];
  bf16_t* lA1 = &As[(wave * 32 + 16) * 32];
  bf16_t* lB0 = &Bs[(wave * 32) * 32];
  bf16_t* lB1 = &Bs[(wave * 32 + 16) * 32];

  fx4 acc[4][4];
#pragma unroll
  for (int i = 0; i < 4; i++)
#pragma unroll
    for (int j = 0; j < 4; j++) acc[i][j] = (fx4)0.0f;

  for (int k0 = 0; k0 < DIM; k0 += 32) {
    gll16(gA0 + k0, lA0);
    gll16(gA1 + k0, lA1);
    gll16(gB0 + k0, lB0);
    gll16(gB1 + k0, lB1);
    __syncthreads();
    bf16x8 av[4], bv[4];
#pragma unroll
    for (int i = 0; i < 4; i++) av[i] = *(const bf16x8*)&As[(wr + i * 16 + l15) * 32 + sw8];
#pragma unroll
    for (int j = 0; j < 4; j++) bv[j] = *(const bf16x8*)&Bs[(wc + j * 16 + l15) * 32 + sw8];
#pragma unroll
    for (int i = 0; i < 4; i++)
#pragma unroll
      for (int j = 0; j < 4; j++)
        acc[i][j] = __builtin_amdgcn_mfma_f32_16x16x32_bf16(av[i], bv[j], acc[i][j], 0, 0, 0);
    __syncthreads();
  }
  // combine: out[t] = gate[t] * (acc + be[e]); dropped tokens stay memset-0
#pragma unroll
  for (int i = 0; i < 4; i++)
#pragma unroll
    for (int r = 0; r < 4; r++) {
      int c = c0 + wr + i * 16 + quad * 4 + r;
      if (c < count) {
        int t = tk[c];
        float g = gate[t];
#pragma unroll
        for (int j = 0; j < 4; j++) {
          int col = n0 + wc + j * 16 + l15;
          outp[(size_t)t * DIM + col] = (bf16_t)((acc[i][j][r] + bias[col]) * g);
        }
      }
    }
}

// ---------------- residual mean over S (parallel over S-chunks) ------------
__global__ __launch_bounds__(256) void k_reduce_sent(
    const bf16_t* __restrict__ h, const bf16_t* __restrict__ o2,
    float* __restrict__ sent) {
  const int d = blockIdx.x * 256 + threadIdx.x;
  const int b = blockIdx.y, sc = blockIdx.z;
  const size_t base = ((size_t)b * SEQ + (size_t)sc * 256) * DIM + d;
  float s = 0.f;
  for (int i = 0; i < 256; i++)
    s += (float)h[base + (size_t)i * DIM] + (float)o2[base + (size_t)i * DIM];
  atomicAdd(&sent[b * DIM + d], s * (1.0f / SEQ));
}

// ---------------- loss: -mean_b log_softmax(sent)[b, y[b]] -----------------
__global__ __launch_bounds__(256) void k_loss(
    const float* __restrict__ sent, const int* __restrict__ y,
    float* __restrict__ out) {
  __shared__ float red[256];
  const int tid = threadIdx.x;
  float total = 0.f;
  for (int b = 0; b < BATCH; b++) {
    const float* sb = sent + b * DIM;
    float m = -1e30f;
    for (int d = tid; d < DIM; d += 256) m = fmaxf(m, sb[d]);
    red[tid] = m;
    __syncthreads();
    for (int s = 128; s; s >>= 1) {
      if (tid < s) red[tid] = fmaxf(red[tid], red[tid + s]);
      __syncthreads();
    }
    m = red[0];
    __syncthreads();
    float sum = 0.f;
    for (int d = tid; d < DIM; d += 256) sum += expf(sb[d] - m);
    red[tid] = sum;
    __syncthreads();
    for (int s = 128; s; s >>= 1) {
      if (tid < s) red[tid] += red[tid + s];
      __syncthreads();
    }
    if (tid == 0) total += m + logf(red[0]) - sb[y[b]];
    __syncthreads();
  }
  if (tid == 0) out[0] = total * (1.0f / BATCH);
}

// ---------------------------------------------------------------------------
extern "C" void kernel_launch(void* const* d_in, const int* in_sizes, int n_in,
                              void* d_out, int out_size, void* d_ws, size_t ws_size,
                              hipStream_t stream) {
  (void)in_sizes; (void)n_in; (void)out_size; (void)ws_size;
  const float* x   = (const float*)d_in[0];
  const int*   y   = (const int*)d_in[1];
  const float* W1  = (const float*)d_in[2];
  const float* b1  = (const float*)d_in[3];
  const float* Wg2 = (const float*)d_in[4];
  const float* We2 = (const float*)d_in[5];
  const float* be2 = (const float*)d_in[6];
  const float* Wg3 = (const float*)d_in[7];
  const float* We3 = (const float*)d_in[8];
  const float* be3 = (const float*)d_in[9];

  char* p = (char*)d_ws;
  size_t off = 0;
  auto carve = [&](size_t bytes) -> char* {
    char* r = p + off;
    off += (bytes + 255) & ~(size_t)255;
    return r;
  };
  bf16_t* Wt   = (bf16_t*)carve((size_t)17 * DIM * DIM * 2);  // 0:W1t 1..8:We2t 9..16:We3t
  bf16_t* h    = (bf16_t*)carve((size_t)TOKS * DIM * 2);
  bf16_t* o1   = (bf16_t*)carve((size_t)TOKS * DIM * 2);
  bf16_t* o2   = (bf16_t*)carve((size_t)TOKS * DIM * 2);  // doubles as xb before MoE-3
  int*    idx  = (int*)carve(TOKS * 4);
  float*  gate = (float*)carve(TOKS * 4);
  int*    tok  = (int*)carve(NEXP * CAP * 4);
  int*    cnt  = (int*)carve(NEXP * 4);
  float*  sent = (float*)carve(BATCH * DIM * 4);
  bf16_t* zp   = (bf16_t*)carve(4096);  // zero page for OOB gather rows
  bf16_t* xb   = o2;                    // alias: x-bf16 dead before o2 is born

  hipMemsetAsync(o1, 0, (size_t)TOKS * DIM * 2, stream);
  hipMemsetAsync(zp, 0, 4096, stream);
  hipMemsetAsync(sent, 0, BATCH * DIM * 4, stream);

  // prep: weight transpose+convert, x convert
  k_prep_w<<<dim3(16, 16, 17), 256, 0, stream>>>(W1, We2, We3, Wt);
  k_cvt_x<<<TOKS * DIM / 8 / 256, 256, 0, stream>>>(x, xb);

  // dense pre-layer
  k_gemm_dense<<<dim3(DIM / 128, TOKS / 128), 256, 0, stream>>>(xb, Wt, b1, h);
  hipMemsetAsync(o2, 0, (size_t)TOKS * DIM * 2, stream);  // xb dead; o2 born

  // MoE layer 2
  k_gate<<<TOKS / 4, 256, 0, stream>>>(h, Wg2, idx, gate);
  k_scan<<<1, 256, 0, stream>>>(idx, tok, cnt);
  k_gemm_expert<<<dim3(DIM / 128, CAP / 128, NEXP), 256, 0, stream>>>(
      h, Wt + (size_t)1 * DIM * DIM, be2, tok, cnt, gate, zp, o1);

  // MoE layer 3
  k_gate<<<TOKS / 4, 256, 0, stream>>>(o1, Wg3, idx, gate);
  k_scan<<<1, 256, 0, stream>>>(idx, tok, cnt);
  k_gemm_expert<<<dim3(DIM / 128, CAP / 128, NEXP), 256, 0, stream>>>(
      o1, Wt + (size_t)9 * DIM * DIM, be3, tok, cnt, gate, zp, o2);

  // residual + sentence mean + CE loss
  k_reduce_sent<<<dim3(DIM / 256, BATCH, SEQ / 256), 256, 0, stream>>>(h, o2, sent);
  k_loss<<<1, 256, 0, stream>>>(sent, y, (float*)d_out);
}